// Round 9
// baseline (82.760 us; speedup 1.0000x reference)
//
#include <hip/hip_runtime.h>
#include <hip/hip_fp16.h>
#include <math.h>

#define B_ 4
#define N_ 4096
#define C_ 32
#define S_ 4096
#define KW 512       // k per wave (8 waves k-split in block)
#define NSTEP 16     // 32 k per step

typedef float f32x4 __attribute__((ext_vector_type(4)));
typedef _Float16 f16x8 __attribute__((ext_vector_type(8)));
typedef __fp16 fp16x2 __attribute__((ext_vector_type(2)));
typedef unsigned int uint_t;
typedef unsigned short ushort_t;

#define AS1(p) ((const __attribute__((address_space(1))) void*)(p))
#define AS3(p) ((__attribute__((address_space(3))) void*)(p))

// ws layout
#define XTH_OFF 0
#define PSI_OFF (B_ * C_ * N_ * 2)           // 1 MB
#define WS_NEED (PSI_OFF + B_ * N_ * 4)      // ~1.1 MB

__device__ __forceinline__ uint_t pkrtz(float a, float b) {
    union { fp16x2 h; uint_t w; } u;
    u.h = __builtin_amdgcn_cvt_pkrtz(a, b);
    return u.w;
}

// Accurate reduction (fallback path only)
__device__ __forceinline__ void sincos_ref(float p, float& sn, float& cs) {
    const double INV2PI_D = 0.15915494309189535;
    const float HI = (float)INV2PI_D;
    const float LO = (float)(INV2PI_D - (double)HI);
    float hi = p * HI;
    float e  = fmaf(p, HI, -hi);
    e = fmaf(p, LO, e);
    float k = rintf(hi);
    float r = (hi - k) + e;
    sn = __builtin_amdgcn_sinf(r);
    cs = __builtin_amdgcn_cosf(r);
}

// Prep: x[B][N][C] f32 -> xTh [B][C][N] f16 (RTN), psi[B][N] = t*4095.
// LDS-tiled transpose, coalesced both sides. One block per (64-n slab, b).
__global__ __launch_bounds__(256)
void fudft_prep(const float* __restrict__ x, const float* __restrict__ t,
                ushort_t* __restrict__ xTh, float* __restrict__ psi)
{
    __shared__ ushort_t lds[64][40];   // pad 32->40
    const int tid = threadIdx.x;
    const int n0 = blockIdx.x * 64;
    const int b  = blockIdx.y;

    const float* src = x + ((size_t)b * N_ + n0) * C_;
    const int nl = tid >> 2, c0 = (tid & 3) * 8;
    const float4 v0 = *(const float4*)(src + (size_t)nl * C_ + c0);
    const float4 v1 = *(const float4*)(src + (size_t)nl * C_ + c0 + 4);
    const float vv[8] = {v0.x, v0.y, v0.z, v0.w, v1.x, v1.y, v1.z, v1.w};
    union { ushort_t u[8]; int4 i; } hp;
#pragma unroll
    for (int j = 0; j < 8; ++j) hp.u[j] = __half_as_ushort(__float2half_rn(vv[j]));
    *(int4*)&lds[nl][c0] = hp.i;

    if (tid < 64) psi[b * N_ + n0 + tid] = t[b * N_ + n0 + tid] * (float)(N_ - 1);
    __syncthreads();

    const int c = tid >> 3, oct = tid & 7;   // 32 c-rows x 8 threads
    union { ushort_t u[8]; int4 i; } o;
#pragma unroll
    for (int j = 0; j < 8; ++j) o.u[j] = lds[oct * 8 + j][c];
    *(int4*)(xTh + ((size_t)(b * C_ + c)) * N_ + n0 + oct * 8) = o.i;
}

#define MFMA16(A, Bv, Acc) __builtin_amdgcn_mfma_f32_16x16x32_f16(A, Bv, Acc, 0, 0, 0)

// Main: barrier-free inner loop. Wave = 32 s-rows x 512 k. psi staged once
// into LDS (broadcast ds_reads off the critical path); x B-fragments are
// lane-private VGPR loads with explicit 1-deep prefetch. 8-wave k-split,
// 3-stage LDS tree reduction (32 KB, aliased over psi) at the end.
__global__ __launch_bounds__(512, 6)
void fudft_mfma(const float* __restrict__ freqs,
                const ushort_t* __restrict__ xTh,
                const float* __restrict__ psi,
                float* __restrict__ out)     // [B][S][C]
{
    __shared__ __align__(16) float sred[8192];   // 32 KB: psi[0..4095] then 4 red slots

    const int tid = threadIdx.x;
    const int wk = tid >> 6;           // k-chunk 0..7
    const int wid = wk;
    const int lane = tid & 63;
    const int q = lane >> 4, r = lane & 15;
    const int b = blockIdx.y;
    const int sb = blockIdx.x * 32;

    // ---- stage psi[b][0..4096) into LDS (16 KB), once ----
    {
        const float* pg = psi + (size_t)b * N_;
        // wave-uniform LDS base + lane*16B; per-lane global src
        __builtin_amdgcn_global_load_lds(AS1(pg + tid * 4),        AS3(sred + wid * 256),        16, 0, 0);
        __builtin_amdgcn_global_load_lds(AS1(pg + 2048 + tid * 4), AS3(sred + 2048 + wid * 256), 16, 0, 0);
    }

    // fast-trig row factor: rev = rr * psi; 2^-12 scale is EXACT.
    const float rr0 = -(freqs[sb + r]      * (float)(N_ - 1)) * 0.000244140625f;
    const float rr1 = -(freqs[sb + 16 + r] * (float)(N_ - 1)) * 0.000244140625f;

    const ushort_t* xb0 = xTh + ((size_t)(b * C_ + r)) * N_ + wk * KW + q * 8;
    const ushort_t* xb1 = xb0 + 16 * N_;
    const float* pl = sred + wk * KW + q * 8;     // LDS psi slice for this wave

    f32x4 aRe0a = {0,0,0,0}, aIm0a = {0,0,0,0}, aRe0b = {0,0,0,0}, aIm0b = {0,0,0,0};
    f32x4 aRe1a = {0,0,0,0}, aIm1a = {0,0,0,0}, aRe1b = {0,0,0,0}, aIm1b = {0,0,0,0};

    // prefetch step 0 x-fragments
    union { int4 i; f16x8 v; } b0c, b1c, b0n, b1n;
    b0c.i = *(const int4*)(xb0);
    b1c.i = *(const int4*)(xb1);

    asm volatile("s_waitcnt vmcnt(0)" ::: "memory");  // psi staged
    __syncthreads();

#pragma unroll 2
    for (int s = 0; s < NSTEP; ++s) {
        if (s + 1 < NSTEP) {
            b0n.i = *(const int4*)(xb0 + (s + 1) * 32);
            b1n.i = *(const int4*)(xb1 + (s + 1) * 32);
        }
        const float4 p0 = *(const float4*)(pl + s * 32);       // ds_read, broadcast
        const float4 p1 = *(const float4*)(pl + s * 32 + 4);

        const float ph[8] = {p0.x, p0.y, p0.z, p0.w, p1.x, p1.y, p1.z, p1.w};
        float c0v[8], s0v[8], c1v[8], s1v[8];
#pragma unroll
        for (int j = 0; j < 8; ++j) {
            float rv0 = __builtin_amdgcn_fractf(rr0 * ph[j]);
            s0v[j] = __builtin_amdgcn_sinf(rv0);               // sin(2*pi*rev)
            c0v[j] = __builtin_amdgcn_cosf(rv0);
            float rv1 = __builtin_amdgcn_fractf(rr1 * ph[j]);
            s1v[j] = __builtin_amdgcn_sinf(rv1);
            c1v[j] = __builtin_amdgcn_cosf(rv1);
        }
        union { uint_t w[4]; f16x8 v; } fC0, fS0, fC1, fS1;
#pragma unroll
        for (int j = 0; j < 4; ++j) {
            fC0.w[j] = pkrtz(c0v[2*j], c0v[2*j+1]);
            fS0.w[j] = pkrtz(s0v[2*j], s0v[2*j+1]);
            fC1.w[j] = pkrtz(c1v[2*j], c1v[2*j+1]);
            fS1.w[j] = pkrtz(s1v[2*j], s1v[2*j+1]);
        }
        aRe0a = MFMA16(fC0.v, b0c.v, aRe0a);  aRe0b = MFMA16(fC0.v, b1c.v, aRe0b);
        aIm0a = MFMA16(fS0.v, b0c.v, aIm0a);  aIm0b = MFMA16(fS0.v, b1c.v, aIm0b);
        aRe1a = MFMA16(fC1.v, b0c.v, aRe1a);  aRe1b = MFMA16(fC1.v, b1c.v, aRe1b);
        aIm1a = MFMA16(fS1.v, b0c.v, aIm1a);  aIm1b = MFMA16(fS1.v, b1c.v, aIm1b);
        b0c = b0n; b1c = b1n;
    }

    // ---- 3-stage tree reduction over wk (slots alias the psi region) ----
    auto store_slot = [&](int slot) {
        float* rb = sred + slot * 2048 + lane * 4;
        *(f32x4*)(rb + 0*256) = aRe0a;  *(f32x4*)(rb + 1*256) = aIm0a;
        *(f32x4*)(rb + 2*256) = aRe0b;  *(f32x4*)(rb + 3*256) = aIm0b;
        *(f32x4*)(rb + 4*256) = aRe1a;  *(f32x4*)(rb + 5*256) = aIm1a;
        *(f32x4*)(rb + 6*256) = aRe1b;  *(f32x4*)(rb + 7*256) = aIm1b;
    };
    auto add_slot = [&](int slot) {
        const float* rb = sred + slot * 2048 + lane * 4;
        aRe0a += *(const f32x4*)(rb + 0*256);  aIm0a += *(const f32x4*)(rb + 1*256);
        aRe0b += *(const f32x4*)(rb + 2*256);  aIm0b += *(const f32x4*)(rb + 3*256);
        aRe1a += *(const f32x4*)(rb + 4*256);  aIm1a += *(const f32x4*)(rb + 5*256);
        aRe1b += *(const f32x4*)(rb + 6*256);  aIm1b += *(const f32x4*)(rb + 7*256);
    };

    __syncthreads();                     // all psi reads done; safe to alias
    if (wk >= 4) store_slot(wk - 4);
    __syncthreads();
    if (wk < 4) add_slot(wk);
    __syncthreads();
    if (wk == 2 || wk == 3) store_slot(wk - 2);
    __syncthreads();
    if (wk < 2) add_slot(wk);
    __syncthreads();
    if (wk == 1) store_slot(0);
    __syncthreads();
    if (wk == 0) {
        add_slot(0);
        // D layout col=lane&15, row=(lane>>4)*4+reg (m89-verified)
        float* po = out + ((size_t)b * S_ + sb) * C_;
#pragma unroll
        for (int reg = 0; reg < 4; ++reg) {
            const int m0 = q * 4 + reg, m1 = 16 + q * 4 + reg;
            const bool z0 = (sb + m0 == 0) || (sb + m0 == S_ - 1);
            const bool z1 = (sb + m1 == 0) || (sb + m1 == S_ - 1);
            float v;
            v = sqrtf(fmaf(aRe0a[reg], aRe0a[reg], aIm0a[reg]*aIm0a[reg])) * 0.015625f;
            po[(size_t)m0 * C_ + r]      = z0 ? 0.f : v;
            v = sqrtf(fmaf(aRe0b[reg], aRe0b[reg], aIm0b[reg]*aIm0b[reg])) * 0.015625f;
            po[(size_t)m0 * C_ + 16 + r] = z0 ? 0.f : v;
            v = sqrtf(fmaf(aRe1a[reg], aRe1a[reg], aIm1a[reg]*aIm1a[reg])) * 0.015625f;
            po[(size_t)m1 * C_ + r]      = z1 ? 0.f : v;
            v = sqrtf(fmaf(aRe1b[reg], aRe1b[reg], aIm1b[reg]*aIm1b[reg])) * 0.015625f;
            po[(size_t)m1 * C_ + 16 + r] = z1 ? 0.f : v;
        }
    }
}

// Safety fallback (only if ws too small — not expected): naive direct kernel.
__global__ __launch_bounds__(256)
void fudft_naive(const float* __restrict__ x, const float* __restrict__ t,
                 const float* __restrict__ freqs, float* __restrict__ out)
{
    const int s = blockIdx.x * 256 + threadIdx.x;
    const int b = blockIdx.y;
    const float row = (freqs[s] * (float)(N_ - 1)) * (float)(-2.0 * M_PI / (double)N_);
    float aR[C_], aI[C_];
#pragma unroll
    for (int c = 0; c < C_; ++c) { aR[c] = 0.f; aI[c] = 0.f; }
    for (int n = 0; n < N_; ++n) {
        const float col = t[b * N_ + n] * (float)(N_ - 1);
        float sn, cs; sincos_ref(row * col, sn, cs);
        const float* xr = x + ((size_t)b * N_ + n) * C_;
#pragma unroll
        for (int c = 0; c < C_; ++c) {
            aR[c] = fmaf(cs, xr[c], aR[c]);
            aI[c] = fmaf(sn, xr[c], aI[c]);
        }
    }
    float* dst = out + ((size_t)b * S_ + s) * C_;
    const bool zero = (s == 0) || (s == S_ - 1);
#pragma unroll
    for (int c = 0; c < C_; ++c) {
        const float m = sqrtf(fmaf(aR[c], aR[c], aI[c] * aI[c])) * 0.015625f;
        dst[c] = zero ? 0.f : m;
    }
}

extern "C" void kernel_launch(void* const* d_in, const int* in_sizes, int n_in,
                              void* d_out, int out_size, void* d_ws, size_t ws_size,
                              hipStream_t stream) {
    const float* x = (const float*)d_in[0];
    const float* t = (const float*)d_in[1];
    const float* f = (const float*)d_in[2];
    float* out = (float*)d_out;

    if (ws_size >= (size_t)WS_NEED) {
        char* ws = (char*)d_ws;
        ushort_t* xTh = (ushort_t*)(ws + XTH_OFF);
        float*    psi = (float*)(ws + PSI_OFF);

        dim3 gprep(N_ / 64, B_);
        fudft_prep<<<gprep, 256, 0, stream>>>(x, t, xTh, psi);
        dim3 grid(S_ / 32, B_);
        fudft_mfma<<<grid, 512, 0, stream>>>(f, xTh, psi, out);
    } else {
        dim3 grid(S_ / 256, B_);
        fudft_naive<<<grid, 256, 0, stream>>>(x, t, f, out);
    }
}

// Round 10
// 82.035 us; speedup vs baseline: 1.0088x; 1.0088x over previous
//
#include <hip/hip_runtime.h>
#include <hip/hip_fp16.h>
#include <math.h>

#define B_ 4
#define N_ 4096
#define C_ 32
#define S_ 4096
#define KW 512       // k per wave (8 waves k-split in block)
#define NSTEP 16     // 32 k per step

typedef float f32x4 __attribute__((ext_vector_type(4)));
typedef _Float16 f16x8 __attribute__((ext_vector_type(8)));
typedef __fp16 fp16x2 __attribute__((ext_vector_type(2)));
typedef unsigned int uint_t;
typedef unsigned short ushort_t;

// ws layout
#define XTH_OFF 0
#define PSI_OFF (B_ * C_ * N_ * 2)           // 1 MB
#define WS_NEED (PSI_OFF + B_ * N_ * 4)      // ~1.1 MB

__device__ __forceinline__ uint_t pkrtz(float a, float b) {
    union { fp16x2 h; uint_t w; } u;
    u.h = __builtin_amdgcn_cvt_pkrtz(a, b);
    return u.w;
}

// Accurate reduction (fallback path only)
__device__ __forceinline__ void sincos_ref(float p, float& sn, float& cs) {
    const double INV2PI_D = 0.15915494309189535;
    const float HI = (float)INV2PI_D;
    const float LO = (float)(INV2PI_D - (double)HI);
    float hi = p * HI;
    float e  = fmaf(p, HI, -hi);
    e = fmaf(p, LO, e);
    float k = rintf(hi);
    float r = (hi - k) + e;
    sn = __builtin_amdgcn_sinf(r);
    cs = __builtin_amdgcn_cosf(r);
}

// Prep: x[B][N][C] f32 -> xTh [B][C][N] f16 (RTN), psi[B][N] = t*4095.
// LDS-tiled transpose, coalesced both sides. One block per (64-n slab, b).
__global__ __launch_bounds__(256)
void fudft_prep(const float* __restrict__ x, const float* __restrict__ t,
                ushort_t* __restrict__ xTh, float* __restrict__ psi)
{
    __shared__ ushort_t lds[64][40];   // pad 32->40
    const int tid = threadIdx.x;
    const int n0 = blockIdx.x * 64;
    const int b  = blockIdx.y;

    const float* src = x + ((size_t)b * N_ + n0) * C_;
    const int nl = tid >> 2, c0 = (tid & 3) * 8;
    const float4 v0 = *(const float4*)(src + (size_t)nl * C_ + c0);
    const float4 v1 = *(const float4*)(src + (size_t)nl * C_ + c0 + 4);
    const float vv[8] = {v0.x, v0.y, v0.z, v0.w, v1.x, v1.y, v1.z, v1.w};
    union { ushort_t u[8]; int4 i; } hp;
#pragma unroll
    for (int j = 0; j < 8; ++j) hp.u[j] = __half_as_ushort(__float2half_rn(vv[j]));
    *(int4*)&lds[nl][c0] = hp.i;

    if (tid < 64) psi[b * N_ + n0 + tid] = t[b * N_ + n0 + tid] * (float)(N_ - 1);
    __syncthreads();

    const int c = tid >> 3, oct = tid & 7;   // 32 c-rows x 8 threads
    union { ushort_t u[8]; int4 i; } o;
#pragma unroll
    for (int j = 0; j < 8; ++j) o.u[j] = lds[oct * 8 + j][c];
    *(int4*)(xTh + ((size_t)(b * C_ + c)) * N_ + n0 + oct * 8) = o.i;
}

#define MFMA16(A, Bv, Acc) __builtin_amdgcn_mfma_f32_16x16x32_f16(A, Bv, Acc, 0, 0, 0)

// Main: barrier-free, FULLY UNROLLED inner loop. Wave = 32 s-rows x 512 k.
// All x/psi loads use immediate offsets off fixed bases; with no barriers the
// scheduler hoists loads multiple steps ahead (deep pipelining for free).
// 8-wave k-split; single flat LDS reduction at the end (the only barrier).
__global__ __launch_bounds__(512, 4)
void fudft_mfma(const float* __restrict__ freqs,
                const ushort_t* __restrict__ xTh,
                const float* __restrict__ psi,
                float* __restrict__ out)     // [B][S][C]
{
    __shared__ float red[14336];   // 7 waves x 8 accs x 64 lanes x f32x4 = 56 KB

    const int tid = threadIdx.x;
    const int wk = tid >> 6;           // k-chunk 0..7
    const int lane = tid & 63;
    const int q = lane >> 4, r = lane & 15;
    const int b = blockIdx.y;
    const int sb = blockIdx.x * 32;

    // fast-trig row factor: rev = rr * psi; 2^-12 scale is EXACT.
    const float rr0 = -(freqs[sb + r]      * (float)(N_ - 1)) * 0.000244140625f;
    const float rr1 = -(freqs[sb + 16 + r] * (float)(N_ - 1)) * 0.000244140625f;

    const float* pp = psi + (size_t)b * N_ + wk * KW + q * 8;
    const ushort_t* xb0 = xTh + ((size_t)(b * C_ + r)) * N_ + wk * KW + q * 8;
    const ushort_t* xb1 = xb0 + 16 * N_;

    f32x4 aRe0a = {0,0,0,0}, aIm0a = {0,0,0,0}, aRe0b = {0,0,0,0}, aIm0b = {0,0,0,0};
    f32x4 aRe1a = {0,0,0,0}, aIm1a = {0,0,0,0}, aRe1b = {0,0,0,0}, aIm1b = {0,0,0,0};

#pragma unroll
    for (int s = 0; s < NSTEP; ++s) {
        const float4 p0 = *(const float4*)(pp + s * 32);       // imm-offset loads
        const float4 p1 = *(const float4*)(pp + s * 32 + 4);
        union { int4 i; f16x8 v; } b0, b1;
        b0.i = *(const int4*)(xb0 + s * 32);
        b1.i = *(const int4*)(xb1 + s * 32);

        const float ph[8] = {p0.x, p0.y, p0.z, p0.w, p1.x, p1.y, p1.z, p1.w};
        float c0v[8], s0v[8], c1v[8], s1v[8];
#pragma unroll
        for (int j = 0; j < 8; ++j) {
            float rv0 = __builtin_amdgcn_fractf(rr0 * ph[j]);
            s0v[j] = __builtin_amdgcn_sinf(rv0);               // sin(2*pi*rev)
            c0v[j] = __builtin_amdgcn_cosf(rv0);
            float rv1 = __builtin_amdgcn_fractf(rr1 * ph[j]);
            s1v[j] = __builtin_amdgcn_sinf(rv1);
            c1v[j] = __builtin_amdgcn_cosf(rv1);
        }
        union { uint_t w[4]; f16x8 v; } fC0, fS0, fC1, fS1;
#pragma unroll
        for (int j = 0; j < 4; ++j) {
            fC0.w[j] = pkrtz(c0v[2*j], c0v[2*j+1]);
            fS0.w[j] = pkrtz(s0v[2*j], s0v[2*j+1]);
            fC1.w[j] = pkrtz(c1v[2*j], c1v[2*j+1]);
            fS1.w[j] = pkrtz(s1v[2*j], s1v[2*j+1]);
        }
        aRe0a = MFMA16(fC0.v, b0.v, aRe0a);  aRe0b = MFMA16(fC0.v, b1.v, aRe0b);
        aIm0a = MFMA16(fS0.v, b0.v, aIm0a);  aIm0b = MFMA16(fS0.v, b1.v, aIm0b);
        aRe1a = MFMA16(fC1.v, b0.v, aRe1a);  aRe1b = MFMA16(fC1.v, b1.v, aRe1b);
        aIm1a = MFMA16(fS1.v, b0.v, aIm1a);  aIm1b = MFMA16(fS1.v, b1.v, aIm1b);
    }

    // ---- single cross-wave reduction over wk = 0..7 ----
    if (wk > 0) {
        float* rb = red + (size_t)(wk - 1) * 8 * 256 + lane * 4;
        *(f32x4*)(rb + 0*256) = aRe0a;  *(f32x4*)(rb + 1*256) = aIm0a;
        *(f32x4*)(rb + 2*256) = aRe0b;  *(f32x4*)(rb + 3*256) = aIm0b;
        *(f32x4*)(rb + 4*256) = aRe1a;  *(f32x4*)(rb + 5*256) = aIm1a;
        *(f32x4*)(rb + 6*256) = aRe1b;  *(f32x4*)(rb + 7*256) = aIm1b;
    }
    __syncthreads();
    if (wk == 0) {
#pragma unroll
        for (int sl = 0; sl < 7; ++sl) {
            const float* rb = red + (size_t)sl * 8 * 256 + lane * 4;
            aRe0a += *(const f32x4*)(rb + 0*256);  aIm0a += *(const f32x4*)(rb + 1*256);
            aRe0b += *(const f32x4*)(rb + 2*256);  aIm0b += *(const f32x4*)(rb + 3*256);
            aRe1a += *(const f32x4*)(rb + 4*256);  aIm1a += *(const f32x4*)(rb + 5*256);
            aRe1b += *(const f32x4*)(rb + 6*256);  aIm1b += *(const f32x4*)(rb + 7*256);
        }
        // D layout col=lane&15, row=(lane>>4)*4+reg (m89-verified)
        float* po = out + ((size_t)b * S_ + sb) * C_;
#pragma unroll
        for (int reg = 0; reg < 4; ++reg) {
            const int m0 = q * 4 + reg, m1 = 16 + q * 4 + reg;
            const bool z0 = (sb + m0 == 0) || (sb + m0 == S_ - 1);
            const bool z1 = (sb + m1 == 0) || (sb + m1 == S_ - 1);
            float v;
            v = sqrtf(fmaf(aRe0a[reg], aRe0a[reg], aIm0a[reg]*aIm0a[reg])) * 0.015625f;
            po[(size_t)m0 * C_ + r]      = z0 ? 0.f : v;
            v = sqrtf(fmaf(aRe0b[reg], aRe0b[reg], aIm0b[reg]*aIm0b[reg])) * 0.015625f;
            po[(size_t)m0 * C_ + 16 + r] = z0 ? 0.f : v;
            v = sqrtf(fmaf(aRe1a[reg], aRe1a[reg], aIm1a[reg]*aIm1a[reg])) * 0.015625f;
            po[(size_t)m1 * C_ + r]      = z1 ? 0.f : v;
            v = sqrtf(fmaf(aRe1b[reg], aRe1b[reg], aIm1b[reg]*aIm1b[reg])) * 0.015625f;
            po[(size_t)m1 * C_ + 16 + r] = z1 ? 0.f : v;
        }
    }
}

// Safety fallback (only if ws too small — not expected): naive direct kernel.
__global__ __launch_bounds__(256)
void fudft_naive(const float* __restrict__ x, const float* __restrict__ t,
                 const float* __restrict__ freqs, float* __restrict__ out)
{
    const int s = blockIdx.x * 256 + threadIdx.x;
    const int b = blockIdx.y;
    const float row = (freqs[s] * (float)(N_ - 1)) * (float)(-2.0 * M_PI / (double)N_);
    float aR[C_], aI[C_];
#pragma unroll
    for (int c = 0; c < C_; ++c) { aR[c] = 0.f; aI[c] = 0.f; }
    for (int n = 0; n < N_; ++n) {
        const float col = t[b * N_ + n] * (float)(N_ - 1);
        float sn, cs; sincos_ref(row * col, sn, cs);
        const float* xr = x + ((size_t)b * N_ + n) * C_;
#pragma unroll
        for (int c = 0; c < C_; ++c) {
            aR[c] = fmaf(cs, xr[c], aR[c]);
            aI[c] = fmaf(sn, xr[c], aI[c]);
        }
    }
    float* dst = out + ((size_t)b * S_ + s) * C_;
    const bool zero = (s == 0) || (s == S_ - 1);
#pragma unroll
    for (int c = 0; c < C_; ++c) {
        const float m = sqrtf(fmaf(aR[c], aR[c], aI[c] * aI[c])) * 0.015625f;
        dst[c] = zero ? 0.f : m;
    }
}

extern "C" void kernel_launch(void* const* d_in, const int* in_sizes, int n_in,
                              void* d_out, int out_size, void* d_ws, size_t ws_size,
                              hipStream_t stream) {
    const float* x = (const float*)d_in[0];
    const float* t = (const float*)d_in[1];
    const float* f = (const float*)d_in[2];
    float* out = (float*)d_out;

    if (ws_size >= (size_t)WS_NEED) {
        char* ws = (char*)d_ws;
        ushort_t* xTh = (ushort_t*)(ws + XTH_OFF);
        float*    psi = (float*)(ws + PSI_OFF);

        dim3 gprep(N_ / 64, B_);
        fudft_prep<<<gprep, 256, 0, stream>>>(x, t, xTh, psi);
        dim3 grid(S_ / 32, B_);
        fudft_mfma<<<grid, 512, 0, stream>>>(f, xTh, psi, out);
    } else {
        dim3 grid(S_ / 256, B_);
        fudft_naive<<<grid, 256, 0, stream>>>(x, t, f, out);
    }
}